// Round 2
// baseline (646.205 us; speedup 1.0000x reference)
//
#include <hip/hip_runtime.h>
#include <hip/hip_bf16.h>
#include <stdint.h>

// RelationalMSG: out = x + relu([x;agg]@W2+b2), agg = segsum(relu([x_s;x_d]@W1+b1), dst)
// N=50000, D=128, E=600000.
// R2: barrier-free wave-independent tiles. W (frag-ordered bf16) staged to LDS once per
// block; each wave processes a 32-row tile across all 128 output cols. A-fragments
// gathered per-lane from global; atomics fire-and-forget (no barrier ever drains them).

typedef __attribute__((ext_vector_type(8))) short short8;   // 8 bf16 = 4 VGPRs (MFMA A/B frag)
typedef __attribute__((ext_vector_type(4))) float floatx4;  // MFMA C/D frag

#define D 128
#define K2 256          // concat dim

static __device__ __forceinline__ unsigned short f2bf(float f) {
    union { float f; unsigned int u; } v; v.f = f;
    unsigned int r = (v.u + 0x7fffu + ((v.u >> 16) & 1u)) >> 16; // RNE
    return (unsigned short)r;
}

__global__ void k_convert_x(const float* __restrict__ x, unsigned short* __restrict__ xb, int n4) {
    int i = blockIdx.x * blockDim.x + threadIdx.x;
    if (i < n4) {
        float4 v = ((const float4*)x)[i];
        ushort4 o;
        o.x = f2bf(v.x); o.y = f2bf(v.y); o.z = f2bf(v.z); o.w = f2bf(v.w);
        ((ushort4*)xb)[i] = o;
    }
}

// W [K2][D] fp32 -> bf16 B-fragment order:
// frag[(kk*8+n)*64+lane][j] = W[kk*32+(lane>>4)*8+j][n*16+(lane&15)]
// Converts W1 (tid<32768) and W2 (tid>=32768) in one launch.
__global__ void k_convert_w(const float* __restrict__ W1, const float* __restrict__ W2,
                            unsigned short* __restrict__ w1f, unsigned short* __restrict__ w2f) {
    int gid = blockIdx.x * blockDim.x + threadIdx.x; // 65536 threads
    const float* W = (gid < 32768) ? W1 : W2;
    unsigned short* wf = (gid < 32768) ? w1f : w2f;
    int tid = gid & 32767;
    int j = tid & 7;
    int lane = (tid >> 3) & 63;
    int n = (tid >> 9) & 7;
    int kk = tid >> 12;
    int k = kk * 32 + (lane >> 4) * 8 + j;
    int c = n * 16 + (lane & 15);
    wf[tid] = f2bf(W[k * D + c]);
}

// Edge message kernel. Block = 8 waves, W1 frags in LDS (64KB, staged once).
// Each wave: 32-edge tile x all 128 cols. acc[2 mt][8 ct] (64 VGPRs).
__global__ __launch_bounds__(512, 4) void k_edge(
    const unsigned short* __restrict__ xb,
    const int* __restrict__ src,
    const int* __restrict__ dst,
    const unsigned short* __restrict__ w1f,
    const float* __restrict__ b1,
    float* __restrict__ agg,
    int E)
{
    __shared__ short8 wlds[4096];   // 64 KB: all of W1 in fragment order
    const int tid = threadIdx.x;
#pragma unroll
    for (int i = 0; i < 8; i++) {
        int idx = i * 512 + tid;
        wlds[idx] = ((const short8*)w1f)[idx];
    }
    __syncthreads();   // the ONLY barrier

    const int lane = tid & 63;
    const int quad = lane >> 4, col = lane & 15;
    const int waveId = blockIdx.x * 8 + (tid >> 6);
    const int nWaves = gridDim.x * 8;

    float bias[8];
#pragma unroll
    for (int ct = 0; ct < 8; ct++) bias[ct] = b1[ct * 16 + col];

    const int nTiles = (E + 31) / 32;
    for (int wt = waveId; wt < nTiles; wt += nWaves) {
        const int e0 = wt * 32;
        // A-row node indices (A layout: m = lane&15)
        int sa[2], da[2];
#pragma unroll
        for (int mt = 0; mt < 2; mt++) {
            int e = e0 + mt * 16 + col; if (e >= E) e = E - 1;
            sa[mt] = src[e]; da[mt] = dst[e];
        }
        // output-row dst indices (C layout: row = quad*4+r)
        int dout[2][4];
#pragma unroll
        for (int mt = 0; mt < 2; mt++)
#pragma unroll
            for (int r = 0; r < 4; r++) {
                int e = e0 + mt * 16 + quad * 4 + r; if (e >= E) e = E - 1;
                dout[mt][r] = dst[e];
            }

        floatx4 acc[2][8];
#pragma unroll
        for (int mt = 0; mt < 2; mt++)
#pragma unroll
            for (int ct = 0; ct < 8; ct++)
#pragma unroll
                for (int q = 0; q < 4; q++) acc[mt][ct][q] = 0.f;

#pragma unroll
        for (int kk = 0; kk < 8; kk++) {
            const int koff = (kk & 3) * 32 + quad * 8;  // offset within 128-wide half
            short8 a0, a1;
            if (kk < 4) {
                a0 = *(const short8*)(xb + (long)sa[0] * D + koff);
                a1 = *(const short8*)(xb + (long)sa[1] * D + koff);
            } else {
                a0 = *(const short8*)(xb + (long)da[0] * D + koff);
                a1 = *(const short8*)(xb + (long)da[1] * D + koff);
            }
#pragma unroll
            for (int ct = 0; ct < 8; ct++) {
                short8 w = wlds[(kk * 8 + ct) * 64 + lane];
                acc[0][ct] = __builtin_amdgcn_mfma_f32_16x16x32_bf16(a0, w, acc[0][ct], 0, 0, 0);
                acc[1][ct] = __builtin_amdgcn_mfma_f32_16x16x32_bf16(a1, w, acc[1][ct], 0, 0, 0);
            }
        }

        // scatter relu(msg): fire-and-forget atomics, skip zeros
#pragma unroll
        for (int mt = 0; mt < 2; mt++)
#pragma unroll
            for (int r = 0; r < 4; r++) {
                bool ok = (e0 + mt * 16 + quad * 4 + r) < E;
                long base = (long)dout[mt][r] * D;
#pragma unroll
                for (int ct = 0; ct < 8; ct++) {
                    float v = acc[mt][ct][r] + bias[ct];
                    if (ok && v > 0.f)
                        atomicAdd(&agg[base + ct * 16 + col], v);
                }
            }
    }
}

// Node update kernel. Same skeleton; rows = [xb[node] ; bf16(agg[node])].
__global__ __launch_bounds__(512, 4) void k_node(
    const unsigned short* __restrict__ xb,
    const float* __restrict__ x,
    const float* __restrict__ agg,
    const unsigned short* __restrict__ w2f,
    const float* __restrict__ b2,
    float* __restrict__ out,
    int N)
{
    __shared__ short8 wlds[4096];
    const int tid = threadIdx.x;
#pragma unroll
    for (int i = 0; i < 8; i++) {
        int idx = i * 512 + tid;
        wlds[idx] = ((const short8*)w2f)[idx];
    }
    __syncthreads();

    const int lane = tid & 63;
    const int quad = lane >> 4, col = lane & 15;
    const int waveId = blockIdx.x * 8 + (tid >> 6);
    const int nWaves = gridDim.x * 8;

    float bias[8];
#pragma unroll
    for (int ct = 0; ct < 8; ct++) bias[ct] = b2[ct * 16 + col];

    const int nTiles = (N + 31) / 32;
    for (int wt = waveId; wt < nTiles; wt += nWaves) {
        const int n0 = wt * 32;
        int na[2];
#pragma unroll
        for (int mt = 0; mt < 2; mt++) {
            int n = n0 + mt * 16 + col; if (n >= N) n = N - 1;
            na[mt] = n;
        }

        floatx4 acc[2][8];
#pragma unroll
        for (int mt = 0; mt < 2; mt++)
#pragma unroll
            for (int ct = 0; ct < 8; ct++)
#pragma unroll
                for (int q = 0; q < 4; q++) acc[mt][ct][q] = 0.f;

#pragma unroll
        for (int kk = 0; kk < 8; kk++) {
            const int koff = (kk & 3) * 32 + quad * 8;
            short8 a[2];
            if (kk < 4) {
#pragma unroll
                for (int mt = 0; mt < 2; mt++)
                    a[mt] = *(const short8*)(xb + (long)na[mt] * D + koff);
            } else {
#pragma unroll
                for (int mt = 0; mt < 2; mt++) {
                    const float* p = agg + (long)na[mt] * D + koff;
                    float4 f0 = *(const float4*)p;
                    float4 f1 = *(const float4*)(p + 4);
                    short8 t;
                    t[0] = (short)f2bf(f0.x); t[1] = (short)f2bf(f0.y);
                    t[2] = (short)f2bf(f0.z); t[3] = (short)f2bf(f0.w);
                    t[4] = (short)f2bf(f1.x); t[5] = (short)f2bf(f1.y);
                    t[6] = (short)f2bf(f1.z); t[7] = (short)f2bf(f1.w);
                    a[mt] = t;
                }
            }
#pragma unroll
            for (int ct = 0; ct < 8; ct++) {
                short8 w = wlds[(kk * 8 + ct) * 64 + lane];
                acc[0][ct] = __builtin_amdgcn_mfma_f32_16x16x32_bf16(a[0], w, acc[0][ct], 0, 0, 0);
                acc[1][ct] = __builtin_amdgcn_mfma_f32_16x16x32_bf16(a[1], w, acc[1][ct], 0, 0, 0);
            }
        }

#pragma unroll
        for (int mt = 0; mt < 2; mt++)
#pragma unroll
            for (int r = 0; r < 4; r++) {
                int node = n0 + mt * 16 + quad * 4 + r;
                if (node < N) {
                    long base = (long)node * D;
#pragma unroll
                    for (int ct = 0; ct < 8; ct++) {
                        float v = acc[mt][ct][r] + bias[ct];
                        v = v > 0.f ? v : 0.f;
                        long idx = base + ct * 16 + col;
                        out[idx] = x[idx] + v;
                    }
                }
            }
    }
}

extern "C" void kernel_launch(void* const* d_in, const int* in_sizes, int n_in,
                              void* d_out, int out_size, void* d_ws, size_t ws_size,
                              hipStream_t stream)
{
    const float* x   = (const float*)d_in[0];
    const int* esrc  = (const int*)d_in[1];
    const int* edst  = (const int*)d_in[2];
    const float* W1  = (const float*)d_in[3];
    const float* b1  = (const float*)d_in[4];
    const float* W2  = (const float*)d_in[5];
    const float* b2  = (const float*)d_in[6];
    float* out = (float*)d_out;

    const int ND = in_sizes[0];   // N*D
    const int N  = ND / D;        // 50000
    const int E  = in_sizes[1];   // 600000

    // workspace: agg fp32 | xb bf16 | w1f | w2f  (all 16B-aligned)
    char* ws = (char*)d_ws;
    float* agg = (float*)ws;
    size_t aggB = (size_t)ND * sizeof(float);
    unsigned short* xb = (unsigned short*)(ws + aggB);
    size_t xbB = (size_t)ND * sizeof(unsigned short);
    unsigned short* w1f = (unsigned short*)(ws + aggB + xbB);
    unsigned short* w2f = w1f + K2 * D;

    hipMemsetAsync(agg, 0, aggB, stream);
    int n4 = ND / 4;
    k_convert_x<<<(n4 + 255) / 256, 256, 0, stream>>>(x, xb, n4);
    k_convert_w<<<256, 256, 0, stream>>>(W1, W2, w1f, w2f);

    // 512 blocks x 512 thr = 4096 waves; 18750 wave-tiles -> ~4.6 tiles/wave
    k_edge<<<512, 512, 0, stream>>>(xb, esrc, edst, w1f, b1, agg, E);

    int nodeTiles = (N + 31) / 32;               // 1563
    int nodeBlocks = (nodeTiles + 7) / 8;        // 196
    k_node<<<nodeBlocks, 512, 0, stream>>>(xb, x, agg, w2f, b2, out, N);
}

// Round 3
// 226.060 us; speedup vs baseline: 2.8586x; 2.8586x over previous
//
#include <hip/hip_runtime.h>
#include <stdint.h>

// RelationalMSG decomposed:
//   msg  = relu(x_s@W1a + x_d@W1b + b1)   ->  Ys = x@W1a, Yd = x@W1b + b1  (dense GEMM)
//   agg  = segment_sum(msg, dst)          ->  counting-sort edges by dst, then CSR
//                                             per-node gather+relu+sum (NO atomics)
//   out  = x + relu([x;agg]@W2 + b2)      ->  dense GEMM
// N=50000 (16 | N), E=600000, D=128.

typedef __attribute__((ext_vector_type(8))) short short8;   // 8 bf16 (MFMA A/B frag)
typedef __attribute__((ext_vector_type(4))) float floatx4;  // MFMA C/D frag

#define D 128

static __device__ __forceinline__ unsigned short f2bf(float f) {
    union { float f; unsigned int u; } v; v.f = f;
    unsigned int r = (v.u + 0x7fffu + ((v.u >> 16) & 1u)) >> 16; // RNE
    return (unsigned short)r;
}
static __device__ __forceinline__ float bflo(unsigned int u) {
    union { unsigned int u; float f; } v; v.u = u << 16; return v.f;
}
static __device__ __forceinline__ float bfhi(unsigned int u) {
    union { unsigned int u; float f; } v; v.u = u & 0xffff0000u; return v.f;
}

__global__ void k_convert_x(const float* __restrict__ x, unsigned short* __restrict__ xb, int n4) {
    int i = blockIdx.x * blockDim.x + threadIdx.x;
    if (i < n4) {
        float4 v = ((const float4*)x)[i];
        ushort4 o;
        o.x = f2bf(v.x); o.y = f2bf(v.y); o.z = f2bf(v.z); o.w = f2bf(v.w);
        ((ushort4*)xb)[i] = o;
    }
}

// B-fragment layouts.
// w1f (gemm1, K=128, 256 out cols): frag[(kk*16+ct)*64+lane][j] = B1[kk*32+(lane>>4)*8+j][ct*16+(lane&15)]
//   B1[k][c] = c<128 ? W1[k][c] : W1[128+k][c-128]   (W1 is [256][128])
// w2f (gemm2, K=256, 128 out cols): frag[(kk*8+ct)*64+lane][j] = W2[kk*32+(lane>>4)*8+j][ct*16+(lane&15)]
__global__ void k_convert_w(const float* __restrict__ W1, const float* __restrict__ W2,
                            unsigned short* __restrict__ w1f, unsigned short* __restrict__ w2f) {
    int gid = blockIdx.x * blockDim.x + threadIdx.x; // 65536 threads
    if (gid < 32768) {
        int tid = gid;
        int j = tid & 7, lane = (tid >> 3) & 63, ct = (tid >> 9) & 15, kk = tid >> 13;
        int k = kk * 32 + (lane >> 4) * 8 + j;
        int c = ct * 16 + (lane & 15);
        float v = (c < 128) ? W1[k * 128 + c] : W1[(128 + k) * 128 + (c - 128)];
        w1f[tid] = f2bf(v);
    } else {
        int tid = gid - 32768;
        int j = tid & 7, lane = (tid >> 3) & 63, ct = (tid >> 9) & 7, kk = tid >> 12;
        int k = kk * 32 + (lane >> 4) * 8 + j;
        int c = ct * 16 + (lane & 15);
        w2f[tid] = f2bf(W2[k * 128 + c]);
    }
}

// Y = x @ [W1a | W1b] (+b1 on the Yd half). M=N, K=128, Nout=256.
// Block = 4 waves; wave w owns out-cols [w*64, w*64+64) (W frags register-resident).
// A-frags read directly from global (contiguous rows -> coalesced). Barrier-free.
__global__ __launch_bounds__(256) void k_gemm1(
    const unsigned short* __restrict__ xb,
    const unsigned short* __restrict__ w1f,
    const float* __restrict__ b1,
    unsigned short* __restrict__ Ys,
    unsigned short* __restrict__ Yd,
    int N, int nTiles)
{
    const int tid = threadIdx.x, w = tid >> 6, lane = tid & 63;
    const int quad = lane >> 4, col = lane & 15;

    short8 wf[4][4];
#pragma unroll
    for (int kk = 0; kk < 4; kk++)
#pragma unroll
        for (int j = 0; j < 4; j++)
            wf[kk][j] = ((const short8*)w1f)[(kk * 16 + w * 4 + j) * 64 + lane];
    float bias[4];
#pragma unroll
    for (int j = 0; j < 4; j++)
        bias[j] = (w >= 2) ? b1[((w - 2) * 4 + j) * 16 + col] : 0.f;
    unsigned short* Yhalf = (w < 2) ? Ys : Yd;
    const int cb = (w & 1) * 64;

    for (int t = blockIdx.x; t < nTiles; t += gridDim.x) {
        const int n0 = t * 16;
        int nr = n0 + col; if (nr >= N) nr = N - 1;
        floatx4 acc[4];
#pragma unroll
        for (int j = 0; j < 4; j++)
#pragma unroll
            for (int q = 0; q < 4; q++) acc[j][q] = 0.f;
#pragma unroll
        for (int kk = 0; kk < 4; kk++) {
            short8 a = *(const short8*)(xb + (long)nr * D + kk * 32 + quad * 8);
#pragma unroll
            for (int j = 0; j < 4; j++)
                acc[j] = __builtin_amdgcn_mfma_f32_16x16x32_bf16(a, wf[kk][j], acc[j], 0, 0, 0);
        }
#pragma unroll
        for (int j = 0; j < 4; j++)
#pragma unroll
            for (int r = 0; r < 4; r++) {
                int n = n0 + quad * 4 + r;
                if (n < N)
                    Yhalf[(long)n * D + cb + j * 16 + col] = f2bf(acc[j][r] + bias[j]);
            }
    }
}

// ---- counting sort of edges by dst ----
__global__ void k_hist(const int* __restrict__ dst, int* __restrict__ cnt, int E) {
    int i = blockIdx.x * blockDim.x + threadIdx.x;
    if (i < E) atomicAdd(&cnt[dst[i]], 1);
}

__global__ void k_scanA(const int* __restrict__ cnt, int* __restrict__ rowptr,
                        int* __restrict__ bsum, int N) {
    __shared__ int s[1024];
    int tid = threadIdx.x, i = blockIdx.x * 1024 + tid;
    int c = (i < N) ? cnt[i] : 0;
    s[tid] = c; __syncthreads();
    for (int off = 1; off < 1024; off <<= 1) {
        int t = (tid >= off) ? s[tid - off] : 0;
        __syncthreads();
        s[tid] += t;
        __syncthreads();
    }
    if (i < N) rowptr[i] = s[tid] - c;           // exclusive within block
    if (tid == 1023) bsum[blockIdx.x] = s[1023]; // block total
}

__global__ void k_scanB(int* __restrict__ bsum, int nb) {
    int lane = threadIdx.x; // single wave of 64; nb <= 64
    int v = (lane < nb) ? bsum[lane] : 0;
    int incl = v;
    for (int off = 1; off < 64; off <<= 1) {
        int t = __shfl_up(incl, off, 64);
        if (lane >= off) incl += t;
    }
    if (lane < nb) bsum[lane] = incl - v;        // exclusive block offsets
}

__global__ void k_scanC(int* __restrict__ rowptr, int* __restrict__ cursor,
                        const int* __restrict__ bsum, int N, int E) {
    int i = blockIdx.x * blockDim.x + threadIdx.x;
    if (i < N) {
        int r = rowptr[i] + bsum[i >> 10];
        rowptr[i] = r;
        cursor[i] = r;
    }
    if (i == 0) rowptr[N] = E;
}

__global__ void k_scatter(const int* __restrict__ src, const int* __restrict__ dst,
                          int* __restrict__ cursor, int* __restrict__ ssrc, int E) {
    int i = blockIdx.x * blockDim.x + threadIdx.x;
    if (i < E) {
        int p = atomicAdd(&cursor[dst[i]], 1);
        ssrc[p] = src[i];
    }
}

// CSR aggregation: one wave per dst node. agg[n] = sum_e relu(Ys[src_e] + Yd[n]).
// Lane handles 2 of 128 cols (bf16x2). Fully coalesced 256B row reads, no atomics.
__global__ __launch_bounds__(256) void k_agg(
    const unsigned short* __restrict__ Ys,
    const unsigned short* __restrict__ Yd,
    const int* __restrict__ rowptr,
    const int* __restrict__ ssrc,
    unsigned short* __restrict__ aggb, int N)
{
    int wv = blockIdx.x * 4 + (threadIdx.x >> 6);
    if (wv >= N) return;
    int lane = threadIdx.x & 63;
    int rp0 = rowptr[wv], rp1 = rowptr[wv + 1];
    unsigned int ydu = *(const unsigned int*)(Yd + (long)wv * D + lane * 2);
    float yd0 = bflo(ydu), yd1 = bfhi(ydu);
    float a0 = 0.f, a1 = 0.f;
    int e = rp0;
    for (; e + 4 <= rp1; e += 4) {
        int s0 = ssrc[e], s1 = ssrc[e + 1], s2 = ssrc[e + 2], s3 = ssrc[e + 3];
        unsigned int u0 = *(const unsigned int*)(Ys + (long)s0 * D + lane * 2);
        unsigned int u1 = *(const unsigned int*)(Ys + (long)s1 * D + lane * 2);
        unsigned int u2 = *(const unsigned int*)(Ys + (long)s2 * D + lane * 2);
        unsigned int u3 = *(const unsigned int*)(Ys + (long)s3 * D + lane * 2);
        a0 += fmaxf(bflo(u0) + yd0, 0.f); a1 += fmaxf(bfhi(u0) + yd1, 0.f);
        a0 += fmaxf(bflo(u1) + yd0, 0.f); a1 += fmaxf(bfhi(u1) + yd1, 0.f);
        a0 += fmaxf(bflo(u2) + yd0, 0.f); a1 += fmaxf(bfhi(u2) + yd1, 0.f);
        a0 += fmaxf(bflo(u3) + yd0, 0.f); a1 += fmaxf(bfhi(u3) + yd1, 0.f);
    }
    for (; e < rp1; e++) {
        int s0 = ssrc[e];
        unsigned int u0 = *(const unsigned int*)(Ys + (long)s0 * D + lane * 2);
        a0 += fmaxf(bflo(u0) + yd0, 0.f); a1 += fmaxf(bfhi(u0) + yd1, 0.f);
    }
    unsigned int o = (unsigned int)f2bf(a0) | ((unsigned int)f2bf(a1) << 16);
    *(unsigned int*)(aggb + (long)wv * D + lane * 2) = o;
}

// out = x + relu([xb ; aggb] @ W2 + b2). M=N, K=256, Nout=128.
// Block = 4 waves; wave w owns out-cols [w*32, w*32+32). Barrier-free.
__global__ __launch_bounds__(256) void k_gemm2(
    const unsigned short* __restrict__ xb,
    const unsigned short* __restrict__ aggb,
    const unsigned short* __restrict__ w2f,
    const float* __restrict__ b2,
    const float* __restrict__ x,
    float* __restrict__ out,
    int N, int nTiles)
{
    const int tid = threadIdx.x, w = tid >> 6, lane = tid & 63;
    const int quad = lane >> 4, col = lane & 15;

    short8 wf[8][2];
#pragma unroll
    for (int kk = 0; kk < 8; kk++)
#pragma unroll
        for (int c = 0; c < 2; c++)
            wf[kk][c] = ((const short8*)w2f)[(kk * 8 + w * 2 + c) * 64 + lane];
    float bias[2];
    bias[0] = b2[(w * 2) * 16 + col];
    bias[1] = b2[(w * 2 + 1) * 16 + col];

    for (int t = blockIdx.x; t < nTiles; t += gridDim.x) {
        const int n0 = t * 16;
        int nr = n0 + col; if (nr >= N) nr = N - 1;
        floatx4 acc[2];
#pragma unroll
        for (int c = 0; c < 2; c++)
#pragma unroll
            for (int q = 0; q < 4; q++) acc[c][q] = 0.f;
#pragma unroll
        for (int kk = 0; kk < 8; kk++) {
            const unsigned short* base = (kk < 4) ? xb : aggb;
            short8 a = *(const short8*)(base + (long)nr * D + (kk & 3) * 32 + quad * 8);
            acc[0] = __builtin_amdgcn_mfma_f32_16x16x32_bf16(a, wf[kk][0], acc[0], 0, 0, 0);
            acc[1] = __builtin_amdgcn_mfma_f32_16x16x32_bf16(a, wf[kk][1], acc[1], 0, 0, 0);
        }
#pragma unroll
        for (int c = 0; c < 2; c++)
#pragma unroll
            for (int r = 0; r < 4; r++) {
                int n = n0 + quad * 4 + r;
                if (n < N) {
                    long idx = (long)n * D + (w * 2 + c) * 16 + col;
                    float v = acc[c][r] + bias[c];
                    v = v > 0.f ? v : 0.f;
                    out[idx] = x[idx] + v;
                }
            }
    }
}

extern "C" void kernel_launch(void* const* d_in, const int* in_sizes, int n_in,
                              void* d_out, int out_size, void* d_ws, size_t ws_size,
                              hipStream_t stream)
{
    const float* x   = (const float*)d_in[0];
    const int* esrc  = (const int*)d_in[1];
    const int* edst  = (const int*)d_in[2];
    const float* W1  = (const float*)d_in[3];
    const float* b1  = (const float*)d_in[4];
    const float* W2  = (const float*)d_in[5];
    const float* b2  = (const float*)d_in[6];
    float* out = (float*)d_out;

    const int ND = in_sizes[0];     // N*D
    const int N  = ND / D;          // 50000
    const int E  = in_sizes[1];     // 600000

    // workspace carve-out (256B-aligned chunks), total ~54 MB
    char* p = (char*)d_ws;
    auto alloc = [&](size_t bytes) { char* r = p; p += (bytes + 255) & ~(size_t)255; return r; };
    unsigned short* Ys   = (unsigned short*)alloc((size_t)ND * 2);
    unsigned short* Yd   = (unsigned short*)alloc((size_t)ND * 2);
    unsigned short* xb   = (unsigned short*)alloc((size_t)ND * 2);
    unsigned short* aggb = (unsigned short*)alloc((size_t)ND * 2);
    unsigned short* w1f  = (unsigned short*)alloc(32768 * 2);
    unsigned short* w2f  = (unsigned short*)alloc(32768 * 2);
    int* rowptr = (int*)alloc((size_t)(N + 1) * 4);
    int* cursor = (int*)alloc((size_t)N * 4);
    int* bsum   = (int*)alloc(64 * 4);
    int* ssrc   = (int*)alloc((size_t)E * 4);

    hipMemsetAsync(cursor, 0, (size_t)N * 4, stream);
    int n4 = ND / 4;
    k_convert_x<<<(n4 + 255) / 256, 256, 0, stream>>>(x, xb, n4);
    k_convert_w<<<256, 256, 0, stream>>>(W1, W2, w1f, w2f);

    const int nTiles = (N + 15) / 16;   // 3125
    k_gemm1<<<640, 256, 0, stream>>>(xb, w1f, b1, Ys, Yd, N, nTiles);

    k_hist<<<(E + 255) / 256, 256, 0, stream>>>(edst, cursor, E);
    const int nb = (N + 1023) / 1024;   // 49 (<=64)
    k_scanA<<<nb, 1024, 0, stream>>>(cursor, rowptr, bsum, N);
    k_scanB<<<1, 64, 0, stream>>>(bsum, nb);
    k_scanC<<<(N + 255) / 256, 256, 0, stream>>>(rowptr, cursor, bsum, N, E);
    k_scatter<<<(E + 255) / 256, 256, 0, stream>>>(esrc, edst, cursor, ssrc, E);

    k_agg<<<(N + 3) / 4, 256, 0, stream>>>(Ys, Yd, rowptr, ssrc, aggb, N);

    k_gemm2<<<640, 256, 0, stream>>>(xb, aggb, w2f, b2, x, out, N, nTiles);
}